// Round 4
// baseline (331.844 us; speedup 1.0000x reference)
//
#include <hip/hip_runtime.h>
#include <hip/hip_bf16.h>

typedef __attribute__((ext_vector_type(8))) __bf16 bf16x8;
typedef __attribute__((ext_vector_type(4))) __bf16 bf16x4;
typedef __attribute__((ext_vector_type(2))) __bf16 bf16x2;
typedef __attribute__((ext_vector_type(4))) float  f32x4;

#define L_SEQ 200
#define LPAD  208   // 13 tiles of 16 rows
#define BPB   8     // batches per block -> grid 512 = 2 blocks/CU exactly

// ---------------------------------------------------------------------------
// Setup 1: Bc[128][128] = [[W1a+W1d],[W1c]] in MFMA-B fragment order, bf16.
// frag layout: ((ct*4+ks)*4+kq)*128 + c*8 + j ; k = ks*32+kq*8+j, col = ct*16+c.
// Batch-independent (32 KB, L2-resident for all main blocks).
// ---------------------------------------------------------------------------
__global__ void setup_bc(const float* __restrict__ W1, __bf16* __restrict__ Bc) {
    const int idx = blockIdx.x * 256 + threadIdx.x;      // 0..16383
    const int j  = idx & 7;
    const int c  = (idx >> 3) & 15;
    const int kq = (idx >> 7) & 3;
    const int ks = (idx >> 9) & 3;
    const int ct = idx >> 11;
    const int k   = ks * 32 + kq * 8 + j;
    const int col = ct * 16 + c;
    float v;
    if (k < 64) v = W1[k * 128 + col] + W1[(192 + k) * 128 + col];   // x path
    else        v = W1[(128 + (k - 64)) * 128 + col];                // x*t path
    Bc[idx] = (__bf16)v;
}

// ---------------------------------------------------------------------------
// Setup 2: TB[B][128] = target @ (W1b - W1d) + b1, fp32.
// ---------------------------------------------------------------------------
__global__ __launch_bounds__(256) void setup_tb(
    const float* __restrict__ target, const float* __restrict__ W1,
    const float* __restrict__ b1, float* __restrict__ TB)
{
    __shared__ float Wbd[64][128];
    __shared__ float Ts[16][64];
    const int tid = threadIdx.x;
    const int b0  = blockIdx.x * 16;
    for (int q = tid; q < 64 * 128; q += 256) {
        const int e = q >> 7, c = q & 127;
        Wbd[e][c] = W1[(64 + e) * 128 + c] - W1[(192 + e) * 128 + c];
    }
    ((float4*)Ts)[tid] = ((const float4*)(target + (size_t)b0 * 64))[tid];
    __syncthreads();
    const int bb = tid >> 4;
    const int c0 = (tid & 15) * 8;
    float acc[8];
    #pragma unroll
    for (int r = 0; r < 8; ++r) acc[r] = b1[c0 + r];
    for (int e = 0; e < 64; ++e) {
        const float tv = Ts[bb][e];
        #pragma unroll
        for (int r = 0; r < 8; ++r) acc[r] += tv * Wbd[e][c0 + r];
    }
    #pragma unroll
    for (int r = 0; r < 8; ++r)
        TB[(size_t)(b0 + bb) * 128 + c0 + r] = acc[r];
}

// ---------------------------------------------------------------------------
// Main: 512 persistent blocks, 8 batches each, double-buffered LDS pipeline.
// Wave w owns col-tiles {2w,2w+1}; K=128 via [x | x*t] (a2/a3 built in regs).
// ---------------------------------------------------------------------------
__global__ __launch_bounds__(256, 2) void din_main(
    const float* __restrict__ behavior,
    const float* __restrict__ target,
    const int*   __restrict__ seqlen,
    const float* __restrict__ W2,
    const __bf16* __restrict__ Bc,
    const float* __restrict__ TB,
    float* __restrict__ out)
{
    __shared__ __align__(16) __bf16 Xbf[2][LPAD * 64];  // 53248 B
    __shared__ float att_part[4][LPAD];                 //  3328 B
    __shared__ float att_s[LPAD];                       //   832 B
    __shared__ float part_s[256];                       //  1024 B
    __shared__ float red_s[8];                          //    32 B -> 58464 B

    const int tid  = threadIdx.x;
    const int lane = tid & 63;
    const int w    = tid >> 6;
    const int kq   = lane >> 4;
    const int c16  = lane & 15;
    const int b0   = blockIdx.x * BPB;

    // --- batch-independent: B fragments (L2-hot) + W2
    bf16x8 bfrag[2][4];
    float w2_l[2];
    #pragma unroll
    for (int i = 0; i < 2; ++i) {
        const int ct = 2 * w + i;
        #pragma unroll
        for (int ks = 0; ks < 4; ++ks)
            bfrag[i][ks] = *(const bf16x8*)(Bc + ((ct * 4 + ks) * 4 + kq) * 128 + c16 * 8);
        w2_l[i] = W2[ct * 16 + c16];
    }
    // --- zero-pad rows 200..207 in BOTH buffers (never overwritten)
    {
        const int row = L_SEQ + (tid >> 5);
        const int e0  = (tid & 31) * 2;
        const int off = row * 64 + (e0 ^ ((row & 7) << 3));
        bf16x2 z = { (__bf16)0.f, (__bf16)0.f };
        *(bf16x2*)&Xbf[0][off] = z;
        *(bf16x2*)&Xbf[1][off] = z;
    }

    // --- prefetch batch b0 into registers
    float4 vn[13];
    float4 tfn[4];
    float  tbn[2];
    {
        const float4* Xg = (const float4*)(behavior + (size_t)b0 * (L_SEQ * 64));
        #pragma unroll
        for (int q = 0; q < 13; ++q) {
            const int idx = tid + q * 256;
            if (q < 12 || idx < L_SEQ * 16) vn[q] = Xg[idx];
        }
        const float* tp = target + (size_t)b0 * 64 + kq * 8;
        tfn[0] = *(const float4*)tp;
        tfn[1] = *(const float4*)(tp + 4);
        tfn[2] = *(const float4*)(tp + 32);
        tfn[3] = *(const float4*)(tp + 36);
        tbn[0] = TB[(size_t)b0 * 128 + (2 * w) * 16 + c16];
        tbn[1] = TB[(size_t)b0 * 128 + (2 * w + 1) * 16 + c16];
    }
    // --- stage batch b0 -> buffer 0
    #pragma unroll
    for (int q = 0; q < 13; ++q) {
        const int idx = tid + q * 256;
        if (q < 12 || idx < L_SEQ * 16) {
            const int row = idx >> 4, j4 = (idx & 15) * 4, sw = (row & 7) << 3;
            float4 v = vn[q];
            bf16x4 u = { (__bf16)v.x, (__bf16)v.y, (__bf16)v.z, (__bf16)v.w };
            *(bf16x4*)&Xbf[0][row * 64 + (j4 ^ sw)] = u;
        }
    }
    __syncthreads();

    for (int i = 0; i < BPB; ++i) {
        const int b   = b0 + i;
        const int cur = i & 1;
        const int sl  = seqlen[b];

        // current batch per-lane params (copy out before tfn/tbn reload)
        float tf0[8], tf1[8], tb_l[2];
        #pragma unroll
        for (int j = 0; j < 4; ++j) {
            tf0[j]     = tfn[0][j];
            tf0[4 + j] = tfn[1][j];
            tf1[j]     = tfn[2][j];
            tf1[4 + j] = tfn[3][j];
        }
        tb_l[0] = tbn[0]; tb_l[1] = tbn[1];

        // --- issue next-batch loads (in flight across GEMM/softmax/wsum)
        if (i + 1 < BPB) {
            const float4* Xg = (const float4*)(behavior + (size_t)(b + 1) * (L_SEQ * 64));
            #pragma unroll
            for (int q = 0; q < 13; ++q) {
                const int idx = tid + q * 256;
                if (q < 12 || idx < L_SEQ * 16) vn[q] = Xg[idx];
            }
            const float* tp = target + (size_t)(b + 1) * 64 + kq * 8;
            tfn[0] = *(const float4*)tp;
            tfn[1] = *(const float4*)(tp + 4);
            tfn[2] = *(const float4*)(tp + 32);
            tfn[3] = *(const float4*)(tp + 36);
            tbn[0] = TB[(size_t)(b + 1) * 128 + (2 * w) * 16 + c16];
            tbn[1] = TB[(size_t)(b + 1) * 128 + (2 * w + 1) * 16 + c16];
        }

        // --- GEMM (software-pipelined A reads) + fused relu/W2-dot
        {
            const __bf16* Xc = &Xbf[cur][0];
            const int sw = (c16 & 7) << 3;          // row&7 == c16&7 each tile
            const int k0 = kq * 8;
            const int o0 = k0 ^ sw, o1 = (k0 + 32) ^ sw;
            const f32x4 zero = {0.f, 0.f, 0.f, 0.f};
            bf16x8 a0 = *(const bf16x8*)&Xc[c16 * 64 + o0];
            bf16x8 a1 = *(const bf16x8*)&Xc[c16 * 64 + o1];
            for (int tile = 0; tile < 13; ++tile) {
                bf16x8 an0, an1;
                if (tile < 12) {
                    const int rb = ((tile + 1) * 16 + c16) * 64;
                    an0 = *(const bf16x8*)&Xc[rb + o0];
                    an1 = *(const bf16x8*)&Xc[rb + o1];
                }
                bf16x8 a2, a3;
                #pragma unroll
                for (int j = 0; j < 8; ++j) {
                    a2[j] = (__bf16)((float)a0[j] * tf0[j]);
                    a3[j] = (__bf16)((float)a1[j] * tf1[j]);
                }
                f32x4 acc0 = zero, acc1 = zero;
                acc0 = __builtin_amdgcn_mfma_f32_16x16x32_bf16(a0, bfrag[0][0], acc0, 0, 0, 0);
                acc0 = __builtin_amdgcn_mfma_f32_16x16x32_bf16(a1, bfrag[0][1], acc0, 0, 0, 0);
                acc0 = __builtin_amdgcn_mfma_f32_16x16x32_bf16(a2, bfrag[0][2], acc0, 0, 0, 0);
                acc0 = __builtin_amdgcn_mfma_f32_16x16x32_bf16(a3, bfrag[0][3], acc0, 0, 0, 0);
                acc1 = __builtin_amdgcn_mfma_f32_16x16x32_bf16(a0, bfrag[1][0], acc1, 0, 0, 0);
                acc1 = __builtin_amdgcn_mfma_f32_16x16x32_bf16(a1, bfrag[1][1], acc1, 0, 0, 0);
                acc1 = __builtin_amdgcn_mfma_f32_16x16x32_bf16(a2, bfrag[1][2], acc1, 0, 0, 0);
                acc1 = __builtin_amdgcn_mfma_f32_16x16x32_bf16(a3, bfrag[1][3], acc1, 0, 0, 0);
                float s[4];
                #pragma unroll
                for (int r = 0; r < 4; ++r)
                    s[r] = fmaxf(acc0[r] + tb_l[0], 0.f) * w2_l[0]
                         + fmaxf(acc1[r] + tb_l[1], 0.f) * w2_l[1];
                #pragma unroll
                for (int r = 0; r < 4; ++r) {       // reduce over 16 C-cols
                    float v = s[r];
                    v += __shfl_xor(v, 1, 64);
                    v += __shfl_xor(v, 2, 64);
                    v += __shfl_xor(v, 4, 64);
                    v += __shfl_xor(v, 8, 64);
                    s[r] = v;
                }
                if (c16 == 0) {
                    const int r0 = tile * 16 + kq * 4;
                    #pragma unroll
                    for (int r = 0; r < 4; ++r) att_part[w][r0 + r] = s[r];
                }
                a0 = an0; a1 = an1;
            }
        }
        __syncthreads();

        // --- masked softmax (b2 dropped: shift-invariant; all-masked -> uniform)
        {
            float val = -INFINITY;
            if (tid < L_SEQ) {
                float v = att_part[0][tid] + att_part[1][tid]
                        + att_part[2][tid] + att_part[3][tid];
                val = (tid < sl) ? v : -1e9f;
            }
            float m = val;
            #pragma unroll
            for (int d = 1; d < 64; d <<= 1) m = fmaxf(m, __shfl_xor(m, d, 64));
            if (lane == 0) red_s[w] = m;
            __syncthreads();
            m = fmaxf(fmaxf(red_s[0], red_s[1]), fmaxf(red_s[2], red_s[3]));
            float p = (tid < L_SEQ) ? __expf(val - m) : 0.f;
            float sum = p;
            #pragma unroll
            for (int d = 1; d < 64; d <<= 1) sum += __shfl_xor(sum, d, 64);
            if (lane == 0) red_s[4 + w] = sum;
            __syncthreads();
            sum = red_s[4] + red_s[5] + red_s[6] + red_s[7];
            const float winv = 1.0f / sum;
            if (tid < LPAD) att_s[tid] = (tid < L_SEQ) ? p * winv : 0.f;
        }
        __syncthreads();

        // --- weighted sum from Xbf[cur]: 7 passes of 32 rows x 8 cols/thread
        {
            const int prow = tid >> 3;
            const int cg   = tid & 7;
            float acc[8] = {0.f,0.f,0.f,0.f,0.f,0.f,0.f,0.f};
            #pragma unroll
            for (int p = 0; p < 7; ++p) {
                const int row = p * 32 + prow;
                if (row < LPAD) {
                    const int sw2 = (row & 7) << 3;
                    bf16x8 xv = *(const bf16x8*)&Xbf[cur][row * 64 + ((cg * 8) ^ sw2)];
                    const float aw = att_s[row];
                    #pragma unroll
                    for (int j = 0; j < 8; ++j) acc[j] += aw * (float)xv[j];
                }
            }
            #pragma unroll
            for (int j = 0; j < 8; ++j) {
                float v = acc[j];
                v += __shfl_xor(v, 8, 64);
                v += __shfl_xor(v, 16, 64);
                v += __shfl_xor(v, 32, 64);
                acc[j] = v;
            }
            if (lane < 8) {
                #pragma unroll
                for (int j = 0; j < 8; ++j) part_s[w * 64 + lane * 8 + j] = acc[j];
            }
        }
        // --- write-late: stage prefetched batch into the other buffer
        if (i + 1 < BPB) {
            #pragma unroll
            for (int q = 0; q < 13; ++q) {
                const int idx = tid + q * 256;
                if (q < 12 || idx < L_SEQ * 16) {
                    const int row = idx >> 4, j4 = (idx & 15) * 4, sw2 = (row & 7) << 3;
                    float4 v = vn[q];
                    bf16x4 u = { (__bf16)v.x, (__bf16)v.y, (__bf16)v.z, (__bf16)v.w };
                    *(bf16x4*)&Xbf[cur ^ 1][row * 64 + (j4 ^ sw2)] = u;
                }
            }
        }
        __syncthreads();
        if (tid < 64)
            out[(size_t)b * 64 + tid] =
                part_s[tid] + part_s[64 + tid] + part_s[128 + tid] + part_s[192 + tid];
    }
}

extern "C" void kernel_launch(void* const* d_in, const int* in_sizes, int n_in,
                              void* d_out, int out_size, void* d_ws, size_t ws_size,
                              hipStream_t stream) {
    (void)n_in; (void)out_size; (void)ws_size;
    const float* behavior = (const float*)d_in[0];
    const float* target   = (const float*)d_in[1];
    const int*   seqlen   = (const int*)d_in[2];
    const float* W1       = (const float*)d_in[3];
    const float* b1       = (const float*)d_in[4];
    const float* W2       = (const float*)d_in[5];
    // d_in[6] = b2: unused (softmax shift-invariance)
    float* out = (float*)d_out;
    const int B = in_sizes[2];   // 4096

    __bf16* Bc = (__bf16*)d_ws;                       // 32 KB
    float*  TB = (float*)((char*)d_ws + 32768);       // B*128*4 = 2 MB

    setup_bc<<<dim3(64), dim3(256), 0, stream>>>(W1, Bc);
    setup_tb<<<dim3(B / 16), dim3(256), 0, stream>>>(target, W1, b1, TB);
    din_main<<<dim3(B / BPB), dim3(256), 0, stream>>>(behavior, target, seqlen, W2, Bc, TB, out);
}